// Round 3
// baseline (108.534 us; speedup 1.0000x reference)
//
#include <hip/hip_runtime.h>
#include <math.h>

// M=100000 nodes, D=64, G=1024 graphs. batch sorted -> contiguous segments.
// out[g] = triu( sum_{m in seg g} a_m * x_m x_m^T ),  a = segment-softmax(x.w+b)

#define DDIM 64
#define NTRI 2080          // 64*65/2
#define CAP  1024          // LDS cache of softmax weights per graph (n ~ 98 +- 10)
#define TILE 32            // nodes per staged tile

__device__ __forceinline__ float dot_row_w(const float* __restrict__ row,
                                           const float* __restrict__ sW) {
    float d = 0.f;
#pragma unroll
    for (int k = 0; k < 16; ++k) {
        const float4 v = ((const float4*)row)[k];
        const float4 w = ((const float4*)sW)[k];
        d = fmaf(v.x, w.x, d); d = fmaf(v.y, w.y, d);
        d = fmaf(v.z, w.z, d); d = fmaf(v.w, w.w, d);
    }
    return d;
}

// ---------------- Kernel A: segment boundaries from sorted batch (tiny)
__global__ void __launch_bounds__(256)
bounds_kernel(const int* __restrict__ batch, int* __restrict__ seg_start, int M, int G)
{
    const int m = blockIdx.x * 256 + threadIdx.x;
    if (m >= M) return;
    const int b0 = batch[m];
    if (m == 0) {
        for (int g = 0; g <= b0; ++g) seg_start[g] = 0;
    } else {
        const int bp = batch[m - 1];
        for (int g = bp + 1; g <= b0; ++g) seg_start[g] = m;
    }
    if (m == M - 1) {
        for (int g = b0 + 1; g <= G; ++g) seg_start[g] = M;
    }
}

// ---------------- Kernel B: fused softmax + sum a_m x x^T per graph
__global__ void __launch_bounds__(256, 4)
sop_kernel(const float* __restrict__ x,
           const float* __restrict__ att_w,
           const float* __restrict__ att_b,
           const int*   __restrict__ seg_start,
           float*       __restrict__ out)
{
    // LDS union:
    //  phase A (softmax + tiles): sA[CAP] | sXr[2][TILE*64] | sYs[2][TILE*64] | sW[64]
    //  phase B (reduce):          red0[4096] | red1[4096]
    __shared__ __align__(16) float smem[CAP + 4 * TILE * DDIM + DDIM];
    float* sA  = smem;                           // softmax weights a_m (scaled)
    float* sXr = smem + CAP;                     // raw x tiles (2 buffers)
    float* sYs = smem + CAP + 2 * TILE * DDIM;   // a-scaled x tiles (2 buffers)
    float* sW  = smem + CAP + 4 * TILE * DDIM;   // w (only for n>CAP fallback)
    __shared__ float sRed[8];

    const int g   = blockIdx.x;
    const int tid = threadIdx.x;
    const int s   = seg_start[g];
    const int n   = seg_start[g + 1] - s;
    float* og = out + (size_t)g * NTRI;

    if (n == 0) {                                // out is poisoned -> write zeros
        for (int i = tid; i < NTRI; i += 256) og[i] = 0.f;
        return;
    }

    // --- phase 1: imp = x.w + b into sA (16 lanes per node, coalesced) ---
    const int lane16 = tid & 15;
    const int grp    = tid >> 4;                 // 0..15
    const float4 wv  = ((const float4*)att_w)[lane16];
    const float  bb  = att_b[0];
    if (tid < DDIM) sW[tid] = att_w[tid];
    const float4* x4 = (const float4*)x;

    for (int idx = grp; idx < n; idx += 16) {
        const float4 v = x4[(size_t)(s + idx) * 16 + lane16];
        float d = fmaf(v.x, wv.x, fmaf(v.y, wv.y, fmaf(v.z, wv.z, v.w * wv.w)));
        d += __shfl_xor(d, 1, 16);
        d += __shfl_xor(d, 2, 16);
        d += __shfl_xor(d, 4, 16);
        d += __shfl_xor(d, 8, 16);
        if (lane16 == 0 && idx < CAP) sA[idx] = d + bb;
    }
    __syncthreads();

    // --- phase 2: softmax stats ---
    const int wid = tid >> 6, lane = tid & 63;
    float lmax = -INFINITY;
    for (int i = tid; i < n; i += 256) {
        const float d = (i < CAP) ? sA[i] : (dot_row_w(x + (size_t)(s + i) * DDIM, sW) + bb);
        lmax = fmaxf(lmax, d);
    }
#pragma unroll
    for (int off = 32; off > 0; off >>= 1) lmax = fmaxf(lmax, __shfl_down(lmax, off, 64));
    if (lane == 0) sRed[wid] = lmax;
    __syncthreads();
    if (tid == 0) sRed[4] = fmaxf(fmaxf(sRed[0], sRed[1]), fmaxf(sRed[2], sRed[3]));
    __syncthreads();
    const float mx = sRed[4];

    float lsum = 0.f;
    for (int i = tid; i < n; i += 256) {
        const float d  = (i < CAP) ? sA[i] : (dot_row_w(x + (size_t)(s + i) * DDIM, sW) + bb);
        const float ev = __expf(d - mx);
        if (i < CAP) sA[i] = ev;
        lsum += ev;
    }
#pragma unroll
    for (int off = 32; off > 0; off >>= 1) lsum += __shfl_down(lsum, off, 64);
    if (lane == 0) sRed[wid] = lsum;
    __syncthreads();
    if (tid == 0) sRed[5] = 1.0f / (sRed[0] + sRed[1] + sRed[2] + sRed[3]);
    __syncthreads();
    const float inv = sRed[5];
    for (int i = tid; i < n && i < CAP; i += 256) sA[i] *= inv;   // sA = a_m
    __syncthreads();

    // --- phase 3: each WAVE owns a full 64x64 acc (8x8/thread), nodes strided by 4 ---
    const int i0 = (lane & 7) * 8;
    const int j0 = (lane >> 3) * 8;
    float acc[8][8];
#pragma unroll
    for (int a = 0; a < 8; ++a)
#pragma unroll
        for (int b = 0; b < 8; ++b) acc[a][b] = 0.f;

    const int T = (n + TILE - 1) / TILE;
    float4 r0, r1;
    {
        const int nt0 = min(TILE, n);
        const size_t base = (size_t)s * 16;
        const float4 z = {0.f, 0.f, 0.f, 0.f};
        r0 = (tid       < nt0 * 16) ? x4[base + tid]       : z;
        r1 = (tid + 256 < nt0 * 16) ? x4[base + tid + 256] : z;
    }

    for (int t = 0; t < T; ++t) {
        const int t0  = t * TILE;
        const int nt  = min(TILE, n - t0);
        const int cur = t & 1;
        float* xb = sXr + cur * TILE * DDIM;
        float* yb = sYs + cur * TILE * DDIM;

        // stage raw + a-scaled copies
        {
            const int g0 = t0 + (tid >> 4);
            const int g1 = t0 + ((tid + 256) >> 4);
            float c0 = 0.f, c1 = 0.f;
            if (g0 < n) c0 = (g0 < CAP) ? sA[g0] : __expf(dot_row_w(x + (size_t)(s + g0) * DDIM, sW) + bb - mx) * inv;
            if (g1 < n) c1 = (g1 < CAP) ? sA[g1] : __expf(dot_row_w(x + (size_t)(s + g1) * DDIM, sW) + bb - mx) * inv;
            ((float4*)xb)[tid]       = r0;
            ((float4*)xb)[tid + 256] = r1;
            float4 y0 = {c0 * r0.x, c0 * r0.y, c0 * r0.z, c0 * r0.w};
            float4 y1 = {c1 * r1.x, c1 * r1.y, c1 * r1.z, c1 * r1.w};
            ((float4*)yb)[tid]       = y0;
            ((float4*)yb)[tid + 256] = y1;
        }
        if (t + 1 < T) {                 // register prefetch of next tile
            const int t0n = t0 + TILE;
            const int ntn = min(TILE, n - t0n);
            const size_t base = (size_t)(s + t0n) * 16;
            const float4 z = {0.f, 0.f, 0.f, 0.f};
            r0 = (tid       < ntn * 16) ? x4[base + tid]       : z;
            r1 = (tid + 256 < ntn * 16) ? x4[base + tid + 256] : z;
        }
        __syncthreads();                 // single barrier per tile (double buffer)

        for (int nn = wid; nn < nt; nn += 4) {
            float yv[8], xv[8];
            *(float4*)&yv[0] = *(const float4*)&yb[nn * DDIM + i0];
            *(float4*)&yv[4] = *(const float4*)&yb[nn * DDIM + i0 + 4];
            *(float4*)&xv[0] = *(const float4*)&xb[nn * DDIM + j0];
            *(float4*)&xv[4] = *(const float4*)&xb[nn * DDIM + j0 + 4];
#pragma unroll
            for (int a = 0; a < 8; ++a)
#pragma unroll
                for (int b = 0; b < 8; ++b)
                    acc[a][b] = fmaf(yv[a], xv[b], acc[a][b]);
        }
    }
    __syncthreads();                     // all tile reads done; LDS is reusable

    // --- phase 4: cross-wave reduce via ping-pong, then triu scatter ---
    float* red0 = smem;                  // [4096]
    float* red1 = smem + 4096;           // [4096]
    if (wid == 0) {
#pragma unroll
        for (int a = 0; a < 8; ++a) {
            *(float4*)&red0[(i0 + a) * DDIM + j0]     = *(const float4*)&acc[a][0];
            *(float4*)&red0[(i0 + a) * DDIM + j0 + 4] = *(const float4*)&acc[a][4];
        }
    } else if (wid == 1) {
#pragma unroll
        for (int a = 0; a < 8; ++a) {
            *(float4*)&red1[(i0 + a) * DDIM + j0]     = *(const float4*)&acc[a][0];
            *(float4*)&red1[(i0 + a) * DDIM + j0 + 4] = *(const float4*)&acc[a][4];
        }
    }
    __syncthreads();
    if (wid == 2) {
#pragma unroll
        for (int a = 0; a < 8; ++a) {
            float4 u = *(const float4*)&red0[(i0 + a) * DDIM + j0];
            float4 v = *(const float4*)&red0[(i0 + a) * DDIM + j0 + 4];
            u.x += acc[a][0]; u.y += acc[a][1]; u.z += acc[a][2]; u.w += acc[a][3];
            v.x += acc[a][4]; v.y += acc[a][5]; v.z += acc[a][6]; v.w += acc[a][7];
            *(float4*)&red0[(i0 + a) * DDIM + j0]     = u;
            *(float4*)&red0[(i0 + a) * DDIM + j0 + 4] = v;
        }
    } else if (wid == 3) {
#pragma unroll
        for (int a = 0; a < 8; ++a) {
            float4 u = *(const float4*)&red1[(i0 + a) * DDIM + j0];
            float4 v = *(const float4*)&red1[(i0 + a) * DDIM + j0 + 4];
            u.x += acc[a][0]; u.y += acc[a][1]; u.z += acc[a][2]; u.w += acc[a][3];
            v.x += acc[a][4]; v.y += acc[a][5]; v.z += acc[a][6]; v.w += acc[a][7];
            *(float4*)&red1[(i0 + a) * DDIM + j0]     = u;
            *(float4*)&red1[(i0 + a) * DDIM + j0 + 4] = v;
        }
    }
    __syncthreads();

    const int ty = tid >> 4, tx = tid & 15;
    const int fi0 = ty * 4, fj0 = tx * 4;
#pragma unroll
    for (int a = 0; a < 4; ++a) {
        const int i = fi0 + a;
        const int base = i * DDIM - (i * (i - 1)) / 2;   // row start in triu vec
#pragma unroll
        for (int b = 0; b < 4; ++b) {
            const int j = fj0 + b;
            if (j >= i) og[base + (j - i)] = red0[i * DDIM + j] + red1[i * DDIM + j];
        }
    }
}

extern "C" void kernel_launch(void* const* d_in, const int* in_sizes, int n_in,
                              void* d_out, int out_size, void* d_ws, size_t ws_size,
                              hipStream_t stream) {
    const float* x     = (const float*)d_in[0];
    const float* att_w = (const float*)d_in[1];
    const float* att_b = (const float*)d_in[2];
    const int*   batch = (const int*)d_in[3];
    // d_in[4] = edge: dead code in reference
    float* out = (float*)d_out;

    const int M = in_sizes[0] / DDIM;
    const int G = out_size / NTRI;

    int* seg_start = (int*)d_ws;                          // (G+1) ints

    bounds_kernel<<<(M + 255) / 256, 256, 0, stream>>>(batch, seg_start, M, G);
    sop_kernel<<<G, 256, 0, stream>>>(x, att_w, att_b, seg_start, out);
}

// Round 4
// 97.707 us; speedup vs baseline: 1.1108x; 1.1108x over previous
//
#include <hip/hip_runtime.h>
#include <hip/hip_bf16.h>
#include <math.h>

// M=100000 nodes, D=64, G=1024 graphs. batch sorted -> contiguous segments.
// out[g] = triu( sum_{m in seg g} a_m * x_m x_m^T ),  a = segment-softmax(x.w+b)
//        = triu( (diag(a) X_g)^T  X_g )   -> bf16 MFMA over K=n nodes.

#define DDIM 64
#define NTRI 2080          // 64*65/2
#define CAP  1024          // LDS cache of softmax weights (n ~ 98, max ~140)
#define TK   32            // K-tile (nodes per MFMA step)

typedef __bf16 bf16x8 __attribute__((ext_vector_type(8)));
typedef float  f32x4  __attribute__((ext_vector_type(4)));

__device__ __forceinline__ float dot_row_w(const float* __restrict__ row,
                                           const float* __restrict__ sW) {
    float d = 0.f;
#pragma unroll
    for (int k = 0; k < 16; ++k) {
        const float4 v = ((const float4*)row)[k];
        const float4 w = ((const float4*)sW)[k];
        d = fmaf(v.x, w.x, d); d = fmaf(v.y, w.y, d);
        d = fmaf(v.z, w.z, d); d = fmaf(v.w, w.w, d);
    }
    return d;
}

__device__ __forceinline__ unsigned pack_bf16(float a, float b) {
    __hip_bfloat162 h2 = __float22bfloat162_rn(make_float2(a, b)); // a->.x (low)
    return *reinterpret_cast<unsigned*>(&h2);
}

// ---------------- Kernel A: segment boundaries from sorted batch (tiny)
__global__ void __launch_bounds__(256)
bounds_kernel(const int* __restrict__ batch, int* __restrict__ seg_start, int M, int G)
{
    const int m = blockIdx.x * 256 + threadIdx.x;
    if (m >= M) return;
    const int b0 = batch[m];
    if (m == 0) {
        for (int g = 0; g <= b0; ++g) seg_start[g] = 0;
    } else {
        const int bp = batch[m - 1];
        for (int g = bp + 1; g <= b0; ++g) seg_start[g] = m;
    }
    if (m == M - 1) {
        for (int g = b0 + 1; g <= G; ++g) seg_start[g] = M;
    }
}

// ---------------- Kernel B: fused attention-softmax + MFMA second moment
__global__ void __launch_bounds__(256)
sop_kernel(const float* __restrict__ x,
           const float* __restrict__ att_w,
           const float* __restrict__ att_b,
           const int*   __restrict__ seg_start,
           float*       __restrict__ out)
{
    // Tiles stored TRANSPOSED: [feat 0..63][node 0..31] bf16, 16B chunks
    // XOR-swizzled: chunk c of row f lives at position c ^ ((f>>1)&3).
    __shared__ unsigned short sT[2][2][DDIM * TK];   // [buf][A=0/B=1], 16 KiB
    __shared__ float sA[CAP];
    __shared__ float sW[DDIM];
    __shared__ float sRed[8];

    const int g   = blockIdx.x;
    const int tid = threadIdx.x;
    const int s   = seg_start[g];
    const int n   = seg_start[g + 1] - s;
    float* og = out + (size_t)g * NTRI;

    if (n == 0) {                                // out poisoned -> write zeros
        for (int i = tid; i < NTRI; i += 256) og[i] = 0.f;
        return;
    }

    // --- phase 1: imp = x.w + b into sA (16 lanes per node, coalesced) ---
    const int lane16 = tid & 15;
    const int grp16  = tid >> 4;                 // 0..15
    const float4 wv  = ((const float4*)att_w)[lane16];
    const float  bb  = att_b[0];
    if (tid < DDIM) sW[tid] = att_w[tid];
    const float4* x4 = (const float4*)x;

    for (int idx = grp16; idx < n; idx += 16) {
        const float4 v = x4[(size_t)(s + idx) * 16 + lane16];
        float d = fmaf(v.x, wv.x, fmaf(v.y, wv.y, fmaf(v.z, wv.z, v.w * wv.w)));
        d += __shfl_xor(d, 1, 16);
        d += __shfl_xor(d, 2, 16);
        d += __shfl_xor(d, 4, 16);
        d += __shfl_xor(d, 8, 16);
        if (lane16 == 0 && idx < CAP) sA[idx] = d + bb;
    }
    __syncthreads();

    // --- phase 2: softmax over segment ---
    const int wid = tid >> 6, lane = tid & 63;
    float lmax = -INFINITY;
    for (int i = tid; i < n; i += 256) {
        const float d = (i < CAP) ? sA[i] : (dot_row_w(x + (size_t)(s + i) * DDIM, sW) + bb);
        lmax = fmaxf(lmax, d);
    }
#pragma unroll
    for (int off = 32; off > 0; off >>= 1) lmax = fmaxf(lmax, __shfl_down(lmax, off, 64));
    if (lane == 0) sRed[wid] = lmax;
    __syncthreads();
    if (tid == 0) sRed[4] = fmaxf(fmaxf(sRed[0], sRed[1]), fmaxf(sRed[2], sRed[3]));
    __syncthreads();
    const float mx = sRed[4];

    float lsum = 0.f;
    for (int i = tid; i < n; i += 256) {
        const float d  = (i < CAP) ? sA[i] : (dot_row_w(x + (size_t)(s + i) * DDIM, sW) + bb);
        const float ev = __expf(d - mx);
        if (i < CAP) sA[i] = ev;
        lsum += ev;
    }
#pragma unroll
    for (int off = 32; off > 0; off >>= 1) lsum += __shfl_down(lsum, off, 64);
    if (lane == 0) sRed[wid] = lsum;
    __syncthreads();
    if (tid == 0) sRed[5] = 1.0f / (sRed[0] + sRed[1] + sRed[2] + sRed[3]);
    __syncthreads();
    const float inv = sRed[5];
    for (int i = tid; i < CAP && i < n; i += 256) sA[i] *= inv;   // sA[m] = a_m
    __syncthreads();

    // --- phase 3: K-loop, mfma_f32_16x16x32_bf16, wave w owns C rows 16w..16w+15 ---
    const int pp = tid & 15;          // node pair p -> nodes 2p, 2p+1
    const int cc = tid >> 4;          // float4 chunk 0..15 (feats 4cc..4cc+3)
    const int il = lane & 15;
    const int qd = lane >> 4;         // 0..3
    const int sw = qd ^ ((il >> 1) & 3);              // swizzled chunk pos
    const int offA = (16 * wid + il) * TK + (sw << 3);   // ushort offset
    const int offB = il * TK + (sw << 3);                // + jt*16*TK

    f32x4 acc[4];
#pragma unroll
    for (int jt = 0; jt < 4; ++jt) acc[jt] = (f32x4){0.f, 0.f, 0.f, 0.f};

    const int T = (n + TK - 1) / TK;
    float4 p0, p1;
    {
        const int m0 = 2 * pp;
        const float4 z = {0.f, 0.f, 0.f, 0.f};
        p0 = (m0     < n) ? x4[(size_t)(s + m0) * 16 + cc]     : z;
        p1 = (m0 + 1 < n) ? x4[(size_t)(s + m0 + 1) * 16 + cc] : z;
    }

    for (int t = 0; t < T; ++t) {
        const int t0  = t * TK;
        const int cur = t & 1;
        unsigned* A32 = (unsigned*)sT[cur][0];
        unsigned* B32 = (unsigned*)sT[cur][1];

        // softmax weights for this thread's node pair
        const int m0 = t0 + 2 * pp;
        float c0 = 0.f, c1 = 0.f;
        if (m0 < n)
            c0 = (m0 < CAP) ? sA[m0]
               : __expf(dot_row_w(x + (size_t)(s + m0) * DDIM, sW) + bb - mx) * inv;
        if (m0 + 1 < n)
            c1 = (m0 + 1 < CAP) ? sA[m0 + 1]
               : __expf(dot_row_w(x + (size_t)(s + m0 + 1) * DDIM, sW) + bb - mx) * inv;

        // stage transposed bf16 tiles (A = a-scaled, B = raw)
        const float* f0 = (const float*)&p0;
        const float* f1 = (const float*)&p1;
#pragma unroll
        for (int jf = 0; jf < 4; ++jf) {
            const int f   = 4 * cc + jf;
            const int pos = (pp >> 2) ^ ((f >> 1) & 3);
            const int ui  = f * (TK / 2) + (pos << 2) + (pp & 3);
            A32[ui] = pack_bf16(c0 * f0[jf], c1 * f1[jf]);
            B32[ui] = pack_bf16(f0[jf], f1[jf]);
        }

        if (t + 1 < T) {                // register prefetch of next tile
            const int m0n = (t + 1) * TK + 2 * pp;
            const float4 z = {0.f, 0.f, 0.f, 0.f};
            p0 = (m0n     < n) ? x4[(size_t)(s + m0n) * 16 + cc]     : z;
            p1 = (m0n + 1 < n) ? x4[(size_t)(s + m0n + 1) * 16 + cc] : z;
        }
        __syncthreads();                // single barrier per tile (double buffer)

        const unsigned short* As = sT[cur][0];
        const unsigned short* Bs = sT[cur][1];
        const bf16x8 av = *(const bf16x8*)(As + offA);
#pragma unroll
        for (int jt = 0; jt < 4; ++jt) {
            const bf16x8 bv = *(const bf16x8*)(Bs + offB + jt * 16 * TK);
            acc[jt] = __builtin_amdgcn_mfma_f32_16x16x32_bf16(av, bv, acc[jt], 0, 0, 0);
        }
    }

    // --- epilogue: C/D layout col=lane&15, row=(lane>>4)*4+reg -> triu scatter ---
    const int rbase = 16 * wid + qd * 4;
#pragma unroll
    for (int jt = 0; jt < 4; ++jt) {
        const int j = 16 * jt + il;
#pragma unroll
        for (int r = 0; r < 4; ++r) {
            const int i = rbase + r;
            if (j >= i) og[i * DDIM - (i * (i - 1)) / 2 + (j - i)] = acc[jt][r];
        }
    }
}

extern "C" void kernel_launch(void* const* d_in, const int* in_sizes, int n_in,
                              void* d_out, int out_size, void* d_ws, size_t ws_size,
                              hipStream_t stream) {
    const float* x     = (const float*)d_in[0];
    const float* att_w = (const float*)d_in[1];
    const float* att_b = (const float*)d_in[2];
    const int*   batch = (const int*)d_in[3];
    // d_in[4] = edge: dead code in reference
    float* out = (float*)d_out;

    const int M = in_sizes[0] / DDIM;
    const int G = out_size / NTRI;

    int* seg_start = (int*)d_ws;                          // (G+1) ints

    bounds_kernel<<<(M + 255) / 256, 256, 0, stream>>>(batch, seg_start, M, G);
    sop_kernel<<<G, 256, 0, stream>>>(x, att_w, att_b, seg_start, out);
}